// Round 5
// baseline (397.263 us; speedup 1.0000x reference)
//
#include <hip/hip_runtime.h>
#include <hip/hip_bf16.h>

// ---------------------------------------------------------------------------
// GCN-VGAE encoder. Round 5:
//  - packed 4B CSR entry: (src:17 | coef:15 as sign-less bf16) — halves
//    csr_fill scatter traffic (was 53MB WRITE for 6.4MB payload) and halves
//    gather metadata; gather no longer touches dinv.
//  - Hf activations stored bf16 (gather writes bf16; bn_stats/gemm read bf16)
//  - fusions: make_dinv->scan_blocks, cursor<-scan_add (no memcpy),
//    single memset for cnt+stats, vectorized bf16 bn_stats.
// Pipeline: deg -> scan(+dinv) -> csr_fill ->
//   gemm0(x f32,W0)->Mbf -> gather->Hb(bf16) -> stats -> coef
//   gemm1(Hb bn+relu,W1)->Mbf -> gather->Hb -> stats -> coef
//   gemmH(Hb bn+relu,[Wmu|Wlog])->Mbf -> gather->d_out (f32, split)
// ---------------------------------------------------------------------------

static __device__ __forceinline__ unsigned short f2bf(float f) {
    __hip_bfloat16 h = __float2bfloat16(f);
    return *reinterpret_cast<unsigned short*>(&h);
}
static __device__ __forceinline__ float bf_lo(unsigned int u) {
    return __uint_as_float(u << 16);
}
static __device__ __forceinline__ float bf_hi(unsigned int u) {
    return __uint_as_float(u & 0xffff0000u);
}

__global__ __launch_bounds__(256)
void deg_count(const int* __restrict__ ei, int* __restrict__ cnt, int E_) {
    int e = blockIdx.x * 256 + threadIdx.x;
    if (e < E_) atomicAdd(&cnt[ei[E_ + e]], 1);   // row 1 = dst
}

// ---- hierarchical exclusive scan (dinv fused): cnt[0..n) -> rowptr[0..n] ----
__global__ __launch_bounds__(1024)
void scan_blocks(const int* __restrict__ cnt, float* __restrict__ dinv,
                 int* __restrict__ rowptr, int* __restrict__ partials, int n) {
    __shared__ int ls[1024];
    int tid = threadIdx.x;
    int i = blockIdx.x * 1024 + tid;
    int v = (i < n) ? cnt[i] : 0;
    if (i < n) dinv[i] = rsqrtf((float)v + 1.0f);
    ls[tid] = v;
    __syncthreads();
    #pragma unroll
    for (int off = 1; off < 1024; off <<= 1) {
        int t = (tid >= off) ? ls[tid - off] : 0;
        __syncthreads();
        ls[tid] += t;
        __syncthreads();
    }
    if (i < n) rowptr[i] = ls[tid] - v;           // local exclusive
    if (tid == 1023) partials[blockIdx.x] = ls[1023];
}

__global__ __launch_bounds__(1024)
void scan_partials(int* __restrict__ partials, int* __restrict__ rowptr_n,
                   int nb) {
    __shared__ int ls[1024];
    int tid = threadIdx.x;
    int v = (tid < nb) ? partials[tid] : 0;
    ls[tid] = v;
    __syncthreads();
    #pragma unroll
    for (int off = 1; off < 1024; off <<= 1) {
        int t = (tid >= off) ? ls[tid - off] : 0;
        __syncthreads();
        ls[tid] += t;
        __syncthreads();
    }
    if (tid < nb) partials[tid] = ls[tid] - v;    // exclusive block offsets
    if (tid == 1023) *rowptr_n = ls[1023];        // rowptr[n] = E
}

__global__ __launch_bounds__(256)
void scan_add(int* __restrict__ rowptr, int* __restrict__ cursor,
              const int* __restrict__ partials, int n) {
    int i = blockIdx.x * 256 + threadIdx.x;
    if (i < n) {
        int v = rowptr[i] + partials[i >> 10];
        rowptr[i] = v;
        cursor[i] = v;
    }
}

// fill CSR: packed entry (src<<15) | (coef as sign-less bf16, RN)
__global__ __launch_bounds__(256)
void csr_fill(const int* __restrict__ ei, const float* __restrict__ dinv,
              int* __restrict__ cursor, unsigned int* __restrict__ csr, int E_) {
    int e = blockIdx.x * 256 + threadIdx.x;
    if (e >= E_) return;
    int s = ei[e], d = ei[E_ + e];
    float coef = dinv[s] * dinv[d];               // > 0 always
    unsigned int cb = (__float_as_uint(coef) + 0x8000u) >> 16;  // RN to bf16
    int p = atomicAdd(&cursor[d], 1);
    csr[p] = ((unsigned int)s << 15) | (cb & 0x7fffu);
}

// per-column BN coefficients: y = max(v*sc + sh, 0)
__global__ __launch_bounds__(128)
void bn_coef(const float* __restrict__ stats, const float* __restrict__ gamma,
             const float* __restrict__ beta, float* __restrict__ sc,
             float* __restrict__ sh, int n) {
    int c = threadIdx.x;
    float inv_n = 1.0f / (float)n;
    float mean = stats[c] * inv_n;
    float var  = stats[128 + c] * inv_n - mean * mean;
    float s = rsqrtf(var + 1e-5f) * gamma[c];
    sc[c] = s;
    sh[c] = beta[c] - mean * s;
}

// Y(bf16) = act(X) @ W, K=128. XBF: X is bf16 else f32.
// FUSE_BN: act = relu(v*sc+sh). SPLIT_W: W = [Wa|Wb] col-concat (2x 128x64).
template<bool FUSE_BN, bool SPLIT_W, bool XBF>
__global__ __launch_bounds__(256)
void gemm128(const void* __restrict__ Xv, const float* __restrict__ Wa,
             const float* __restrict__ Wb, const float* __restrict__ sc,
             const float* __restrict__ sh, unsigned short* __restrict__ Y,
             int nRows) {
    __shared__ float xs[32][128];
    const int tid = threadIdx.x;
    const int row0 = blockIdx.x * 32;

    if (!XBF) {
        const float* X = (const float*)Xv;
        #pragma unroll
        for (int q = 0; q < 4; ++q) {
            int flat = (q * 256 + tid) * 4;
            int r = flat >> 7, k = flat & 127;
            float4 v = make_float4(0.f, 0.f, 0.f, 0.f);
            if (row0 + r < nRows)
                v = *(const float4*)(X + (size_t)(row0 + r) * 128 + k);
            if (FUSE_BN) {
                float4 s4 = *(const float4*)(sc + k);
                float4 h4 = *(const float4*)(sh + k);
                v.x = fmaxf(v.x * s4.x + h4.x, 0.f);
                v.y = fmaxf(v.y * s4.y + h4.y, 0.f);
                v.z = fmaxf(v.z * s4.z + h4.z, 0.f);
                v.w = fmaxf(v.w * s4.w + h4.w, 0.f);
            }
            *(float4*)&xs[r][k] = v;
        }
    } else {
        const unsigned short* X = (const unsigned short*)Xv;
        #pragma unroll
        for (int q = 0; q < 2; ++q) {
            int flat = (q * 256 + tid) * 8;       // 8 bf16 per thread
            int r = flat >> 7, k = flat & 127;
            uint4 u = make_uint4(0u, 0u, 0u, 0u);
            if (row0 + r < nRows)
                u = *(const uint4*)(X + (size_t)(row0 + r) * 128 + k);
            float v[8] = {bf_lo(u.x), bf_hi(u.x), bf_lo(u.y), bf_hi(u.y),
                          bf_lo(u.z), bf_hi(u.z), bf_lo(u.w), bf_hi(u.w)};
            if (FUSE_BN) {
                float4 sA = *(const float4*)(sc + k);
                float4 sB = *(const float4*)(sc + k + 4);
                float4 hA = *(const float4*)(sh + k);
                float4 hB = *(const float4*)(sh + k + 4);
                v[0] = fmaxf(v[0] * sA.x + hA.x, 0.f);
                v[1] = fmaxf(v[1] * sA.y + hA.y, 0.f);
                v[2] = fmaxf(v[2] * sA.z + hA.z, 0.f);
                v[3] = fmaxf(v[3] * sA.w + hA.w, 0.f);
                v[4] = fmaxf(v[4] * sB.x + hB.x, 0.f);
                v[5] = fmaxf(v[5] * sB.y + hB.y, 0.f);
                v[6] = fmaxf(v[6] * sB.z + hB.z, 0.f);
                v[7] = fmaxf(v[7] * sB.w + hB.w, 0.f);
            }
            #pragma unroll
            for (int j = 0; j < 8; ++j) xs[r][k + j] = v[j];
        }
    }
    __syncthreads();

    const int tx = tid & 31, ty = tid >> 5;
    const int c0 = tx * 4, r0 = ty * 4;
    float acc[4][4] = {};

    for (int k = 0; k < 128; k += 4) {
        float xv[4][4];
        #pragma unroll
        for (int i = 0; i < 4; ++i)
            *(float4*)xv[i] = *(const float4*)&xs[r0 + i][k];
        #pragma unroll
        for (int j = 0; j < 4; ++j) {
            int kk = k + j;
            float4 wv;
            if (!SPLIT_W) {
                wv = *(const float4*)(Wa + kk * 128 + c0);
            } else {
                wv = (c0 < 64) ? *(const float4*)(Wa + kk * 64 + c0)
                               : *(const float4*)(Wb + kk * 64 + (c0 - 64));
            }
            #pragma unroll
            for (int i = 0; i < 4; ++i) {
                acc[i][0] += xv[i][j] * wv.x;
                acc[i][1] += xv[i][j] * wv.y;
                acc[i][2] += xv[i][j] * wv.z;
                acc[i][3] += xv[i][j] * wv.w;
            }
        }
    }

    #pragma unroll
    for (int i = 0; i < 4; ++i) {
        int r = row0 + r0 + i;
        if (r >= nRows) continue;
        ushort4 o;
        o.x = f2bf(acc[i][0]); o.y = f2bf(acc[i][1]);
        o.z = f2bf(acc[i][2]); o.w = f2bf(acc[i][3]);
        *(ushort4*)(Y + (size_t)r * 128 + c0) = o;
    }
}

// O[d,:] = dinv[d]^2 * M[d,:] + sum_k coef_k * M[src_k,:]   (M bf16)
// one wave per dst row; lane owns channels {2l, 2l+1}; unroll x4.
// TO_OUT: write f32 split halves [z_mean | z_log]; else write bf16 Hb.
template<bool TO_OUT>
__global__ __launch_bounds__(256)
void gather_bf(const unsigned short* __restrict__ M,
               const int* __restrict__ rowptr,
               const unsigned int* __restrict__ csr,
               const float* __restrict__ dinv, void* __restrict__ O, int n) {
    int wid  = (blockIdx.x * 256 + threadIdx.x) >> 6;
    int lane = threadIdx.x & 63;
    if (wid >= n) return;
    const unsigned int* m2 = (const unsigned int*)M;   // 2 bf16 per uint

    float di = dinv[wid];
    unsigned int su = m2[(size_t)wid * 64 + lane];
    float c = di * di;
    float a0x = bf_lo(su) * c, a0y = bf_hi(su) * c;
    float a1x = 0.f, a1y = 0.f, a2x = 0.f, a2y = 0.f, a3x = 0.f, a3y = 0.f;

    int beg = __builtin_amdgcn_readfirstlane(rowptr[wid]);
    int end = __builtin_amdgcn_readfirstlane(rowptr[wid + 1]);

    int k = beg;
    for (; k + 3 < end; k += 4) {
        unsigned int e0 = csr[k],     e1 = csr[k + 1];
        unsigned int e2 = csr[k + 2], e3 = csr[k + 3];
        unsigned int u0 = m2[(size_t)(e0 >> 15) * 64 + lane];
        unsigned int u1 = m2[(size_t)(e1 >> 15) * 64 + lane];
        unsigned int u2 = m2[(size_t)(e2 >> 15) * 64 + lane];
        unsigned int u3 = m2[(size_t)(e3 >> 15) * 64 + lane];
        float w0 = __uint_as_float((e0 & 0x7fffu) << 16);
        float w1 = __uint_as_float((e1 & 0x7fffu) << 16);
        float w2 = __uint_as_float((e2 & 0x7fffu) << 16);
        float w3 = __uint_as_float((e3 & 0x7fffu) << 16);
        a0x += w0 * bf_lo(u0); a0y += w0 * bf_hi(u0);
        a1x += w1 * bf_lo(u1); a1y += w1 * bf_hi(u1);
        a2x += w2 * bf_lo(u2); a2y += w2 * bf_hi(u2);
        a3x += w3 * bf_lo(u3); a3y += w3 * bf_hi(u3);
    }
    for (; k < end; ++k) {
        unsigned int e0 = csr[k];
        unsigned int u0 = m2[(size_t)(e0 >> 15) * 64 + lane];
        float w0 = __uint_as_float((e0 & 0x7fffu) << 16);
        a0x += w0 * bf_lo(u0); a0y += w0 * bf_hi(u0);
    }
    float ax = (a0x + a1x) + (a2x + a3x);
    float ay = (a0y + a1y) + (a2y + a3y);

    if (!TO_OUT) {
        unsigned int o = (unsigned int)f2bf(ax) | ((unsigned int)f2bf(ay) << 16);
        ((unsigned int*)O)[(size_t)wid * 64 + lane] = o;
    } else {
        float* Of = (float*)O;
        float* dst = (lane < 32)
            ? Of + (size_t)wid * 64 + 2 * lane
            : Of + (size_t)n * 64 + (size_t)wid * 64 + 2 * (lane - 32);
        *(float2*)dst = make_float2(ax, ay);
    }
}

// column sums/sumsq over N rows of bf16 H -> stats[0:128]=sum, [128:256]=sumsq
__global__ __launch_bounds__(256)
void bn_stats(const unsigned short* __restrict__ H, float* __restrict__ stats,
              int n) {
    const unsigned int* h2 = (const unsigned int*)H;
    int tid = threadIdx.x;
    int w  = tid & 63;          // word = channels {2w, 2w+1}
    int rg = tid >> 6;          // 0..3
    float s0 = 0.f, q0 = 0.f, s1 = 0.f, q1 = 0.f;
    for (int r = blockIdx.x * 4 + rg; r < n; r += gridDim.x * 4) {
        unsigned int u = h2[(size_t)r * 64 + w];
        float a = bf_lo(u), b = bf_hi(u);
        s0 += a; q0 += a * a; s1 += b; q1 += b * b;
    }
    __shared__ float ls[4][64][4];
    ls[rg][w][0] = s0; ls[rg][w][1] = q0; ls[rg][w][2] = s1; ls[rg][w][3] = q1;
    __syncthreads();
    if (tid < 64) {
        float S0 = 0.f, Q0 = 0.f, S1 = 0.f, Q1 = 0.f;
        #pragma unroll
        for (int g = 0; g < 4; ++g) {
            S0 += ls[g][tid][0]; Q0 += ls[g][tid][1];
            S1 += ls[g][tid][2]; Q1 += ls[g][tid][3];
        }
        atomicAdd(&stats[2 * tid],       S0);
        atomicAdd(&stats[2 * tid + 1],   S1);
        atomicAdd(&stats[128 + 2 * tid], Q0);
        atomicAdd(&stats[129 + 2 * tid], Q1);
    }
}

extern "C" void kernel_launch(void* const* d_in, const int* in_sizes, int n_in,
                              void* d_out, int out_size, void* d_ws, size_t ws_size,
                              hipStream_t stream) {
    const float* x    = (const float*)d_in[0];
    const int*   ei   = (const int*)d_in[1];
    const float* W0   = (const float*)d_in[2];
    const float* W1   = (const float*)d_in[3];
    const float* Wmu  = (const float*)d_in[4];
    const float* Wlog = (const float*)d_in[5];
    const float* g0   = (const float*)d_in[6];
    const float* b0   = (const float*)d_in[7];
    const float* g1   = (const float*)d_in[8];
    const float* b1   = (const float*)d_in[9];

    const int N_ = in_sizes[0] / 128;
    const int E_ = in_sizes[1] / 2;
    float* out = (float*)d_out;

    char* w = (char*)d_ws;
    auto carve = [&](size_t bytes) {
        char* p = w;
        w += (bytes + 255) & ~(size_t)255;
        return p;
    };
    // zeroed region first: cnt | stats0 | stats1 (single memset)
    int*   cnt    = (int*)  carve((size_t)N_ * 4);
    float* stats0 = (float*)carve(256 * 4);
    float* stats1 = (float*)carve(256 * 4);
    char*  zend   = w;
    float* dinv   = (float*)carve((size_t)N_ * 4);
    int*   rowptr = (int*)  carve((size_t)(N_ + 1) * 4);
    int*   cursor = (int*)  carve((size_t)(N_ + 1) * 4);
    int*   partials = (int*)carve(1024 * 4);
    unsigned int* csr = (unsigned int*)carve((size_t)E_ * 4);
    float* sc0    = (float*)carve(128 * 4);
    float* sh0    = (float*)carve(128 * 4);
    float* sc1    = (float*)carve(128 * 4);
    float* sh1    = (float*)carve(128 * 4);
    unsigned short* Mbf = (unsigned short*)carve((size_t)N_ * 128 * 2);
    unsigned short* Hb  = (unsigned short*)carve((size_t)N_ * 128 * 2);

    const int gGemm = (N_ + 31) / 32;
    const int gGath = (N_ * 64 + 255) / 256;       // one wave per node
    const int nb    = (N_ + 1023) / 1024;

    // ---- graph preprocessing: deg -> scan(+dinv) -> csr_fill ----
    hipMemsetAsync(cnt, 0, (size_t)(zend - (char*)cnt), stream);
    deg_count<<<(E_ + 255) / 256, 256, 0, stream>>>(ei, cnt, E_);
    scan_blocks<<<nb, 1024, 0, stream>>>(cnt, dinv, rowptr, partials, N_);
    scan_partials<<<1, 1024, 0, stream>>>(partials, rowptr + N_, nb);
    scan_add<<<(N_ + 255) / 256, 256, 0, stream>>>(rowptr, cursor, partials, N_);
    csr_fill<<<(E_ + 255) / 256, 256, 0, stream>>>(ei, dinv, cursor, csr, E_);

    // ---- layer 0 ----
    gemm128<false, false, false><<<gGemm, 256, 0, stream>>>(
        x, W0, nullptr, nullptr, nullptr, Mbf, N_);
    gather_bf<false><<<gGath, 256, 0, stream>>>(Mbf, rowptr, csr, dinv, Hb, N_);
    bn_stats<<<1024, 256, 0, stream>>>(Hb, stats0, N_);
    bn_coef<<<1, 128, 0, stream>>>(stats0, g0, b0, sc0, sh0, N_);

    // ---- layer 1 (BN0+ReLU fused into GEMM stage) ----
    gemm128<true, false, true><<<gGemm, 256, 0, stream>>>(
        Hb, W1, nullptr, sc0, sh0, Mbf, N_);
    gather_bf<false><<<gGath, 256, 0, stream>>>(Mbf, rowptr, csr, dinv, Hb, N_);
    bn_stats<<<1024, 256, 0, stream>>>(Hb, stats1, N_);
    bn_coef<<<1, 128, 0, stream>>>(stats1, g1, b1, sc1, sh1, N_);

    // ---- heads (BN1+ReLU fused): Mh = relu(BN(Hb)) @ [Wmu|Wlog]; out = A^ Mh
    gemm128<true, true, true><<<gGemm, 256, 0, stream>>>(
        Hb, Wmu, Wlog, sc1, sh1, Mbf, N_);
    gather_bf<true><<<gGath, 256, 0, stream>>>(Mbf, rowptr, csr, dinv, out, N_);
}

// Round 6
// 320.875 us; speedup vs baseline: 1.2381x; 1.2381x over previous
//
#include <hip/hip_runtime.h>
#include <hip/hip_bf16.h>

// ---------------------------------------------------------------------------
// GCN-VGAE encoder. Round 6: bn_stats rewritten for bandwidth (was 54us x2,
// latency-bound at 4B/thread/iter; now uint4 16B loads, block reads a
// contiguous 4KB line per iteration, 512 blocks, LDS reduce + 256 atomics).
// Rest identical to round 5 (packed 4B CSR, bf16 activations, fused BN).
// Pipeline: deg -> scan(+dinv) -> csr_fill ->
//   gemm0(x f32,W0)->Mbf -> gather->Hb(bf16) -> stats -> coef
//   gemm1(Hb bn+relu,W1)->Mbf -> gather->Hb -> stats -> coef
//   gemmH(Hb bn+relu,[Wmu|Wlog])->Mbf -> gather->d_out (f32, split)
// ---------------------------------------------------------------------------

static __device__ __forceinline__ unsigned short f2bf(float f) {
    __hip_bfloat16 h = __float2bfloat16(f);
    return *reinterpret_cast<unsigned short*>(&h);
}
static __device__ __forceinline__ float bf_lo(unsigned int u) {
    return __uint_as_float(u << 16);
}
static __device__ __forceinline__ float bf_hi(unsigned int u) {
    return __uint_as_float(u & 0xffff0000u);
}

__global__ __launch_bounds__(256)
void deg_count(const int* __restrict__ ei, int* __restrict__ cnt, int E_) {
    int e = blockIdx.x * 256 + threadIdx.x;
    if (e < E_) atomicAdd(&cnt[ei[E_ + e]], 1);   // row 1 = dst
}

// ---- hierarchical exclusive scan (dinv fused): cnt[0..n) -> rowptr[0..n] ----
__global__ __launch_bounds__(1024)
void scan_blocks(const int* __restrict__ cnt, float* __restrict__ dinv,
                 int* __restrict__ rowptr, int* __restrict__ partials, int n) {
    __shared__ int ls[1024];
    int tid = threadIdx.x;
    int i = blockIdx.x * 1024 + tid;
    int v = (i < n) ? cnt[i] : 0;
    if (i < n) dinv[i] = rsqrtf((float)v + 1.0f);
    ls[tid] = v;
    __syncthreads();
    #pragma unroll
    for (int off = 1; off < 1024; off <<= 1) {
        int t = (tid >= off) ? ls[tid - off] : 0;
        __syncthreads();
        ls[tid] += t;
        __syncthreads();
    }
    if (i < n) rowptr[i] = ls[tid] - v;           // local exclusive
    if (tid == 1023) partials[blockIdx.x] = ls[1023];
}

__global__ __launch_bounds__(1024)
void scan_partials(int* __restrict__ partials, int* __restrict__ rowptr_n,
                   int nb) {
    __shared__ int ls[1024];
    int tid = threadIdx.x;
    int v = (tid < nb) ? partials[tid] : 0;
    ls[tid] = v;
    __syncthreads();
    #pragma unroll
    for (int off = 1; off < 1024; off <<= 1) {
        int t = (tid >= off) ? ls[tid - off] : 0;
        __syncthreads();
        ls[tid] += t;
        __syncthreads();
    }
    if (tid < nb) partials[tid] = ls[tid] - v;    // exclusive block offsets
    if (tid == 1023) *rowptr_n = ls[1023];        // rowptr[n] = E
}

__global__ __launch_bounds__(256)
void scan_add(int* __restrict__ rowptr, int* __restrict__ cursor,
              const int* __restrict__ partials, int n) {
    int i = blockIdx.x * 256 + threadIdx.x;
    if (i < n) {
        int v = rowptr[i] + partials[i >> 10];
        rowptr[i] = v;
        cursor[i] = v;
    }
}

// fill CSR: packed entry (src<<15) | (coef as sign-less bf16, RN)
__global__ __launch_bounds__(256)
void csr_fill(const int* __restrict__ ei, const float* __restrict__ dinv,
              int* __restrict__ cursor, unsigned int* __restrict__ csr, int E_) {
    int e = blockIdx.x * 256 + threadIdx.x;
    if (e >= E_) return;
    int s = ei[e], d = ei[E_ + e];
    float coef = dinv[s] * dinv[d];               // > 0 always
    unsigned int cb = (__float_as_uint(coef) + 0x8000u) >> 16;  // RN to bf16
    int p = atomicAdd(&cursor[d], 1);
    csr[p] = ((unsigned int)s << 15) | (cb & 0x7fffu);
}

// per-column BN coefficients: y = max(v*sc + sh, 0)
__global__ __launch_bounds__(128)
void bn_coef(const float* __restrict__ stats, const float* __restrict__ gamma,
             const float* __restrict__ beta, float* __restrict__ sc,
             float* __restrict__ sh, int n) {
    int c = threadIdx.x;
    float inv_n = 1.0f / (float)n;
    float mean = stats[c] * inv_n;
    float var  = stats[128 + c] * inv_n - mean * mean;
    float s = rsqrtf(var + 1e-5f) * gamma[c];
    sc[c] = s;
    sh[c] = beta[c] - mean * s;
}

// Y(bf16) = act(X) @ W, K=128. XBF: X is bf16 else f32.
// FUSE_BN: act = relu(v*sc+sh). SPLIT_W: W = [Wa|Wb] col-concat (2x 128x64).
template<bool FUSE_BN, bool SPLIT_W, bool XBF>
__global__ __launch_bounds__(256)
void gemm128(const void* __restrict__ Xv, const float* __restrict__ Wa,
             const float* __restrict__ Wb, const float* __restrict__ sc,
             const float* __restrict__ sh, unsigned short* __restrict__ Y,
             int nRows) {
    __shared__ float xs[32][128];
    const int tid = threadIdx.x;
    const int row0 = blockIdx.x * 32;

    if (!XBF) {
        const float* X = (const float*)Xv;
        #pragma unroll
        for (int q = 0; q < 4; ++q) {
            int flat = (q * 256 + tid) * 4;
            int r = flat >> 7, k = flat & 127;
            float4 v = make_float4(0.f, 0.f, 0.f, 0.f);
            if (row0 + r < nRows)
                v = *(const float4*)(X + (size_t)(row0 + r) * 128 + k);
            if (FUSE_BN) {
                float4 s4 = *(const float4*)(sc + k);
                float4 h4 = *(const float4*)(sh + k);
                v.x = fmaxf(v.x * s4.x + h4.x, 0.f);
                v.y = fmaxf(v.y * s4.y + h4.y, 0.f);
                v.z = fmaxf(v.z * s4.z + h4.z, 0.f);
                v.w = fmaxf(v.w * s4.w + h4.w, 0.f);
            }
            *(float4*)&xs[r][k] = v;
        }
    } else {
        const unsigned short* X = (const unsigned short*)Xv;
        #pragma unroll
        for (int q = 0; q < 2; ++q) {
            int flat = (q * 256 + tid) * 8;       // 8 bf16 per thread
            int r = flat >> 7, k = flat & 127;
            uint4 u = make_uint4(0u, 0u, 0u, 0u);
            if (row0 + r < nRows)
                u = *(const uint4*)(X + (size_t)(row0 + r) * 128 + k);
            float v[8] = {bf_lo(u.x), bf_hi(u.x), bf_lo(u.y), bf_hi(u.y),
                          bf_lo(u.z), bf_hi(u.z), bf_lo(u.w), bf_hi(u.w)};
            if (FUSE_BN) {
                float4 sA = *(const float4*)(sc + k);
                float4 sB = *(const float4*)(sc + k + 4);
                float4 hA = *(const float4*)(sh + k);
                float4 hB = *(const float4*)(sh + k + 4);
                v[0] = fmaxf(v[0] * sA.x + hA.x, 0.f);
                v[1] = fmaxf(v[1] * sA.y + hA.y, 0.f);
                v[2] = fmaxf(v[2] * sA.z + hA.z, 0.f);
                v[3] = fmaxf(v[3] * sA.w + hA.w, 0.f);
                v[4] = fmaxf(v[4] * sB.x + hB.x, 0.f);
                v[5] = fmaxf(v[5] * sB.y + hB.y, 0.f);
                v[6] = fmaxf(v[6] * sB.z + hB.z, 0.f);
                v[7] = fmaxf(v[7] * sB.w + hB.w, 0.f);
            }
            #pragma unroll
            for (int j = 0; j < 8; ++j) xs[r][k + j] = v[j];
        }
    }
    __syncthreads();

    const int tx = tid & 31, ty = tid >> 5;
    const int c0 = tx * 4, r0 = ty * 4;
    float acc[4][4] = {};

    for (int k = 0; k < 128; k += 4) {
        float xv[4][4];
        #pragma unroll
        for (int i = 0; i < 4; ++i)
            *(float4*)xv[i] = *(const float4*)&xs[r0 + i][k];
        #pragma unroll
        for (int j = 0; j < 4; ++j) {
            int kk = k + j;
            float4 wv;
            if (!SPLIT_W) {
                wv = *(const float4*)(Wa + kk * 128 + c0);
            } else {
                wv = (c0 < 64) ? *(const float4*)(Wa + kk * 64 + c0)
                               : *(const float4*)(Wb + kk * 64 + (c0 - 64));
            }
            #pragma unroll
            for (int i = 0; i < 4; ++i) {
                acc[i][0] += xv[i][j] * wv.x;
                acc[i][1] += xv[i][j] * wv.y;
                acc[i][2] += xv[i][j] * wv.z;
                acc[i][3] += xv[i][j] * wv.w;
            }
        }
    }

    #pragma unroll
    for (int i = 0; i < 4; ++i) {
        int r = row0 + r0 + i;
        if (r >= nRows) continue;
        ushort4 o;
        o.x = f2bf(acc[i][0]); o.y = f2bf(acc[i][1]);
        o.z = f2bf(acc[i][2]); o.w = f2bf(acc[i][3]);
        *(ushort4*)(Y + (size_t)r * 128 + c0) = o;
    }
}

// O[d,:] = dinv[d]^2 * M[d,:] + sum_k coef_k * M[src_k,:]   (M bf16)
// one wave per dst row; lane owns channels {2l, 2l+1}; unroll x4.
// TO_OUT: write f32 split halves [z_mean | z_log]; else write bf16 Hb.
template<bool TO_OUT>
__global__ __launch_bounds__(256)
void gather_bf(const unsigned short* __restrict__ M,
               const int* __restrict__ rowptr,
               const unsigned int* __restrict__ csr,
               const float* __restrict__ dinv, void* __restrict__ O, int n) {
    int wid  = (blockIdx.x * 256 + threadIdx.x) >> 6;
    int lane = threadIdx.x & 63;
    if (wid >= n) return;
    const unsigned int* m2 = (const unsigned int*)M;   // 2 bf16 per uint

    float di = dinv[wid];
    unsigned int su = m2[(size_t)wid * 64 + lane];
    float c = di * di;
    float a0x = bf_lo(su) * c, a0y = bf_hi(su) * c;
    float a1x = 0.f, a1y = 0.f, a2x = 0.f, a2y = 0.f, a3x = 0.f, a3y = 0.f;

    int beg = __builtin_amdgcn_readfirstlane(rowptr[wid]);
    int end = __builtin_amdgcn_readfirstlane(rowptr[wid + 1]);

    int k = beg;
    for (; k + 3 < end; k += 4) {
        unsigned int e0 = csr[k],     e1 = csr[k + 1];
        unsigned int e2 = csr[k + 2], e3 = csr[k + 3];
        unsigned int u0 = m2[(size_t)(e0 >> 15) * 64 + lane];
        unsigned int u1 = m2[(size_t)(e1 >> 15) * 64 + lane];
        unsigned int u2 = m2[(size_t)(e2 >> 15) * 64 + lane];
        unsigned int u3 = m2[(size_t)(e3 >> 15) * 64 + lane];
        float w0 = __uint_as_float((e0 & 0x7fffu) << 16);
        float w1 = __uint_as_float((e1 & 0x7fffu) << 16);
        float w2 = __uint_as_float((e2 & 0x7fffu) << 16);
        float w3 = __uint_as_float((e3 & 0x7fffu) << 16);
        a0x += w0 * bf_lo(u0); a0y += w0 * bf_hi(u0);
        a1x += w1 * bf_lo(u1); a1y += w1 * bf_hi(u1);
        a2x += w2 * bf_lo(u2); a2y += w2 * bf_hi(u2);
        a3x += w3 * bf_lo(u3); a3y += w3 * bf_hi(u3);
    }
    for (; k < end; ++k) {
        unsigned int e0 = csr[k];
        unsigned int u0 = m2[(size_t)(e0 >> 15) * 64 + lane];
        float w0 = __uint_as_float((e0 & 0x7fffu) << 16);
        a0x += w0 * bf_lo(u0); a0y += w0 * bf_hi(u0);
    }
    float ax = (a0x + a1x) + (a2x + a3x);
    float ay = (a0y + a1y) + (a2y + a3y);

    if (!TO_OUT) {
        unsigned int o = (unsigned int)f2bf(ax) | ((unsigned int)f2bf(ay) << 16);
        ((unsigned int*)O)[(size_t)wid * 64 + lane] = o;
    } else {
        float* Of = (float*)O;
        float* dst = (lane < 32)
            ? Of + (size_t)wid * 64 + 2 * lane
            : Of + (size_t)n * 64 + (size_t)wid * 64 + 2 * (lane - 32);
        *(float2*)dst = make_float2(ax, ay);
    }
}

// column sums/sumsq over N rows of bf16 H (N x 128) -> stats[0:128]=sum,
// [128:256]=sumsq. Block reads contiguous 4KB per iteration (uint4/thread):
// thread (rg=tid>>4, cg=tid&15) covers row blockIdx*16+rg, channels cg*8..+7.
__global__ __launch_bounds__(256)
void bn_stats(const unsigned short* __restrict__ H, float* __restrict__ stats,
              int n) {
    const uint4* h4 = (const uint4*)H;            // 8 bf16 per uint4, 16/row
    const int tid = threadIdx.x;
    const int cg = tid & 15;                      // channel group (8 ch)
    const int rg = tid >> 4;                      // row-in-block 0..15
    float s[8] = {}, q[8] = {};
    for (int r = blockIdx.x * 16 + rg; r < n; r += gridDim.x * 16) {
        uint4 u = h4[(size_t)r * 16 + cg];        // flat = blk*256+tid: coalesced
        float v[8] = {bf_lo(u.x), bf_hi(u.x), bf_lo(u.y), bf_hi(u.y),
                      bf_lo(u.z), bf_hi(u.z), bf_lo(u.w), bf_hi(u.w)};
        #pragma unroll
        for (int j = 0; j < 8; ++j) { s[j] += v[j]; q[j] += v[j] * v[j]; }
    }
    __shared__ float ls[256][17];                 // pad to dodge bank aliasing
    #pragma unroll
    for (int j = 0; j < 8; ++j) { ls[tid][j] = s[j]; ls[tid][8 + j] = q[j]; }
    __syncthreads();
    if (tid < 128) {
        int c = tid, cgrp = c >> 3, j = c & 7;
        float S = 0.f, Q = 0.f;
        #pragma unroll
        for (int g = 0; g < 16; ++g) {
            S += ls[(g << 4) | cgrp][j];
            Q += ls[(g << 4) | cgrp][8 + j];
        }
        atomicAdd(&stats[c], S);
        atomicAdd(&stats[128 + c], Q);
    }
}

extern "C" void kernel_launch(void* const* d_in, const int* in_sizes, int n_in,
                              void* d_out, int out_size, void* d_ws, size_t ws_size,
                              hipStream_t stream) {
    const float* x    = (const float*)d_in[0];
    const int*   ei   = (const int*)d_in[1];
    const float* W0   = (const float*)d_in[2];
    const float* W1   = (const float*)d_in[3];
    const float* Wmu  = (const float*)d_in[4];
    const float* Wlog = (const float*)d_in[5];
    const float* g0   = (const float*)d_in[6];
    const float* b0   = (const float*)d_in[7];
    const float* g1   = (const float*)d_in[8];
    const float* b1   = (const float*)d_in[9];

    const int N_ = in_sizes[0] / 128;
    const int E_ = in_sizes[1] / 2;
    float* out = (float*)d_out;

    char* w = (char*)d_ws;
    auto carve = [&](size_t bytes) {
        char* p = w;
        w += (bytes + 255) & ~(size_t)255;
        return p;
    };
    // zeroed region first: cnt | stats0 | stats1 (single memset)
    int*   cnt    = (int*)  carve((size_t)N_ * 4);
    float* stats0 = (float*)carve(256 * 4);
    float* stats1 = (float*)carve(256 * 4);
    char*  zend   = w;
    float* dinv   = (float*)carve((size_t)N_ * 4);
    int*   rowptr = (int*)  carve((size_t)(N_ + 1) * 4);
    int*   cursor = (int*)  carve((size_t)(N_ + 1) * 4);
    int*   partials = (int*)carve(1024 * 4);
    unsigned int* csr = (unsigned int*)carve((size_t)E_ * 4);
    float* sc0    = (float*)carve(128 * 4);
    float* sh0    = (float*)carve(128 * 4);
    float* sc1    = (float*)carve(128 * 4);
    float* sh1    = (float*)carve(128 * 4);
    unsigned short* Mbf = (unsigned short*)carve((size_t)N_ * 128 * 2);
    unsigned short* Hb  = (unsigned short*)carve((size_t)N_ * 128 * 2);

    const int gGemm = (N_ + 31) / 32;
    const int gGath = (N_ * 64 + 255) / 256;       // one wave per node
    const int nb    = (N_ + 1023) / 1024;

    // ---- graph preprocessing: deg -> scan(+dinv) -> csr_fill ----
    hipMemsetAsync(cnt, 0, (size_t)(zend - (char*)cnt), stream);
    deg_count<<<(E_ + 255) / 256, 256, 0, stream>>>(ei, cnt, E_);
    scan_blocks<<<nb, 1024, 0, stream>>>(cnt, dinv, rowptr, partials, N_);
    scan_partials<<<1, 1024, 0, stream>>>(partials, rowptr + N_, nb);
    scan_add<<<(N_ + 255) / 256, 256, 0, stream>>>(rowptr, cursor, partials, N_);
    csr_fill<<<(E_ + 255) / 256, 256, 0, stream>>>(ei, dinv, cursor, csr, E_);

    // ---- layer 0 ----
    gemm128<false, false, false><<<gGemm, 256, 0, stream>>>(
        x, W0, nullptr, nullptr, nullptr, Mbf, N_);
    gather_bf<false><<<gGath, 256, 0, stream>>>(Mbf, rowptr, csr, dinv, Hb, N_);
    bn_stats<<<512, 256, 0, stream>>>(Hb, stats0, N_);
    bn_coef<<<1, 128, 0, stream>>>(stats0, g0, b0, sc0, sh0, N_);

    // ---- layer 1 (BN0+ReLU fused into GEMM stage) ----
    gemm128<true, false, true><<<gGemm, 256, 0, stream>>>(
        Hb, W1, nullptr, sc0, sh0, Mbf, N_);
    gather_bf<false><<<gGath, 256, 0, stream>>>(Mbf, rowptr, csr, dinv, Hb, N_);
    bn_stats<<<512, 256, 0, stream>>>(Hb, stats1, N_);
    bn_coef<<<1, 128, 0, stream>>>(stats1, g1, b1, sc1, sh1, N_);

    // ---- heads (BN1+ReLU fused): Mh = relu(BN(Hb)) @ [Wmu|Wlog]; out = A^ Mh
    gemm128<true, true, true><<<gGemm, 256, 0, stream>>>(
        Hb, Wmu, Wlog, sc1, sh1, Mbf, N_);
    gather_bf<true><<<gGath, 256, 0, stream>>>(Mbf, rowptr, csr, dinv, out, N_);
}

// Round 7
// 270.680 us; speedup vs baseline: 1.4677x; 1.1854x over previous
//
#include <hip/hip_runtime.h>
#include <hip/hip_bf16.h>

// ---------------------------------------------------------------------------
// GCN-VGAE encoder. Round 7: GEMMs moved to MFMA (mfma_f32_16x16x32_bf16).
//  - block = 128 rows x 128 cols, 4 waves, per wave 2 M-frags x 8 N-frags
//  - A-frags read directly from global (16B/lane, full 64B-line utilization)
//  - W staged per block into LDS [c][k] bf16 with XOR swizzle k^((c&7)<<3)
//    (unswizzled would be 16-way bank conflict on ds_read_b128; swz -> 2-way)
//  - BN+ReLU fused into A-frag unpack (gemm1/gemmH)
// Rest identical to round 6 (packed 4B CSR, bf16 activations, fast bn_stats).
// ---------------------------------------------------------------------------

using short8 = __attribute__((ext_vector_type(8))) short;
using f32x4  = __attribute__((ext_vector_type(4))) float;

static __device__ __forceinline__ unsigned short f2bf(float f) {
    __hip_bfloat16 h = __float2bfloat16(f);
    return *reinterpret_cast<unsigned short*>(&h);
}
static __device__ __forceinline__ float bf_lo(unsigned int u) {
    return __uint_as_float(u << 16);
}
static __device__ __forceinline__ float bf_hi(unsigned int u) {
    return __uint_as_float(u & 0xffff0000u);
}
static __device__ __forceinline__ float bf2f(unsigned short u) {
    return __uint_as_float((unsigned int)u << 16);
}

__global__ __launch_bounds__(256)
void deg_count(const int* __restrict__ ei, int* __restrict__ cnt, int E_) {
    int e = blockIdx.x * 256 + threadIdx.x;
    if (e < E_) atomicAdd(&cnt[ei[E_ + e]], 1);   // row 1 = dst
}

// ---- hierarchical exclusive scan (dinv fused): cnt[0..n) -> rowptr[0..n] ----
__global__ __launch_bounds__(1024)
void scan_blocks(const int* __restrict__ cnt, float* __restrict__ dinv,
                 int* __restrict__ rowptr, int* __restrict__ partials, int n) {
    __shared__ int ls[1024];
    int tid = threadIdx.x;
    int i = blockIdx.x * 1024 + tid;
    int v = (i < n) ? cnt[i] : 0;
    if (i < n) dinv[i] = rsqrtf((float)v + 1.0f);
    ls[tid] = v;
    __syncthreads();
    #pragma unroll
    for (int off = 1; off < 1024; off <<= 1) {
        int t = (tid >= off) ? ls[tid - off] : 0;
        __syncthreads();
        ls[tid] += t;
        __syncthreads();
    }
    if (i < n) rowptr[i] = ls[tid] - v;           // local exclusive
    if (tid == 1023) partials[blockIdx.x] = ls[1023];
}

__global__ __launch_bounds__(1024)
void scan_partials(int* __restrict__ partials, int* __restrict__ rowptr_n,
                   int nb) {
    __shared__ int ls[1024];
    int tid = threadIdx.x;
    int v = (tid < nb) ? partials[tid] : 0;
    ls[tid] = v;
    __syncthreads();
    #pragma unroll
    for (int off = 1; off < 1024; off <<= 1) {
        int t = (tid >= off) ? ls[tid - off] : 0;
        __syncthreads();
        ls[tid] += t;
        __syncthreads();
    }
    if (tid < nb) partials[tid] = ls[tid] - v;    // exclusive block offsets
    if (tid == 1023) *rowptr_n = ls[1023];        // rowptr[n] = E
}

__global__ __launch_bounds__(256)
void scan_add(int* __restrict__ rowptr, int* __restrict__ cursor,
              const int* __restrict__ partials, int n) {
    int i = blockIdx.x * 256 + threadIdx.x;
    if (i < n) {
        int v = rowptr[i] + partials[i >> 10];
        rowptr[i] = v;
        cursor[i] = v;
    }
}

// fill CSR: packed entry (src<<15) | (coef as sign-less bf16, RN)
__global__ __launch_bounds__(256)
void csr_fill(const int* __restrict__ ei, const float* __restrict__ dinv,
              int* __restrict__ cursor, unsigned int* __restrict__ csr, int E_) {
    int e = blockIdx.x * 256 + threadIdx.x;
    if (e >= E_) return;
    int s = ei[e], d = ei[E_ + e];
    float coef = dinv[s] * dinv[d];               // > 0 always
    unsigned int cb = (__float_as_uint(coef) + 0x8000u) >> 16;  // RN to bf16
    int p = atomicAdd(&cursor[d], 1);
    csr[p] = ((unsigned int)s << 15) | (cb & 0x7fffu);
}

// per-column BN coefficients: y = max(v*sc + sh, 0)
__global__ __launch_bounds__(128)
void bn_coef(const float* __restrict__ stats, const float* __restrict__ gamma,
             const float* __restrict__ beta, float* __restrict__ sc,
             float* __restrict__ sh, int n) {
    int c = threadIdx.x;
    float inv_n = 1.0f / (float)n;
    float mean = stats[c] * inv_n;
    float var  = stats[128 + c] * inv_n - mean * mean;
    float s = rsqrtf(var + 1e-5f) * gamma[c];
    sc[c] = s;
    sh[c] = beta[c] - mean * s;
}

// ---------------------------------------------------------------------------
// MFMA GEMM: Y(bf16 N x 128) = act(X) @ W, K=128.
// XBF: X bf16 else f32. FUSE_BN: act = relu(v*sc+sh).
// SPLIT_W: W = [Wa | Wb] column-concat (each 128x64 f32).
// Layout (mfma_f32_16x16x32_bf16, verified m89):
//   A: row = lane&15, k = (lane>>4)*8 + j    (short8, 16B global load)
//   B: col = lane&15, k = (lane>>4)*8 + j    (short8 from swizzled LDS)
//   D: col = lane&15, row = (lane>>4)*4 + reg
// ---------------------------------------------------------------------------
template<bool XBF, bool FUSE_BN, bool SPLIT_W>
__global__ __launch_bounds__(256)
void gemm_mfma(const void* __restrict__ Xv, const float* __restrict__ Wa,
               const float* __restrict__ Wb, const float* __restrict__ sc,
               const float* __restrict__ sh, unsigned short* __restrict__ Y,
               int nRows) {
    __shared__ unsigned short wt[128 * 128];  // [c][k] bf16, k XOR-swizzled

    const int tid = threadIdx.x;

    // stage W (f32 [k][c]) -> wt[c*128 + (k ^ ((c&7)<<3))]
    #pragma unroll
    for (int it = 0; it < 16; ++it) {
        int flat4 = it * 256 + tid;          // float4 index over 16384 floats
        int k  = flat4 >> 5;
        int c0 = (flat4 & 31) * 4;
        const float* srcp;
        if (!SPLIT_W) srcp = Wa + k * 128 + c0;
        else          srcp = (c0 < 64) ? (Wa + k * 64 + c0)
                                       : (Wb + k * 64 + (c0 - 64));
        float4 v = *(const float4*)srcp;
        float vv[4] = {v.x, v.y, v.z, v.w};
        #pragma unroll
        for (int j = 0; j < 4; ++j) {
            int c = c0 + j;
            wt[c * 128 + (k ^ ((c & 7) << 3))] = f2bf(vv[j]);
        }
    }
    __syncthreads();

    const int lane = tid & 63;
    const int wv   = tid >> 6;
    const int lm   = lane & 15;              // frag row (A) / col (B,D)
    const int lg   = lane >> 4;              // k-group
    const int row0 = blockIdx.x * 128 + wv * 32;

    f32x4 acc[2][8] = {};

    #pragma unroll
    for (int ks = 0; ks < 4; ++ks) {
        const int k0 = ks * 32 + lg * 8;

        short8 a[2];
        #pragma unroll
        for (int mf = 0; mf < 2; ++mf) {
            int r = row0 + mf * 16 + lm;
            if (r < nRows) {
                if (XBF) {
                    a[mf] = *(const short8*)((const unsigned short*)Xv +
                                             (size_t)r * 128 + k0);
                    if (FUSE_BN) {
                        float4 s0 = *(const float4*)(sc + k0);
                        float4 s1 = *(const float4*)(sc + k0 + 4);
                        float4 h0 = *(const float4*)(sh + k0);
                        float4 h1 = *(const float4*)(sh + k0 + 4);
                        float sv[8] = {s0.x, s0.y, s0.z, s0.w, s1.x, s1.y, s1.z, s1.w};
                        float hv[8] = {h0.x, h0.y, h0.z, h0.w, h1.x, h1.y, h1.z, h1.w};
                        #pragma unroll
                        for (int j = 0; j < 8; ++j) {
                            float v = bf2f((unsigned short)a[mf][j]);
                            v = fmaxf(v * sv[j] + hv[j], 0.f);
                            a[mf][j] = (short)f2bf(v);
                        }
                    }
                } else {
                    const float* xp = (const float*)Xv + (size_t)r * 128 + k0;
                    float4 p0 = *(const float4*)xp;
                    float4 p1 = *(const float4*)(xp + 4);
                    float pv[8] = {p0.x, p0.y, p0.z, p0.w, p1.x, p1.y, p1.z, p1.w};
                    #pragma unroll
                    for (int j = 0; j < 8; ++j) a[mf][j] = (short)f2bf(pv[j]);
                }
            } else {
                a[mf] = short8{};
            }
        }

        #pragma unroll
        for (int f = 0; f < 8; ++f) {
            int c = f * 16 + lm;
            short8 b = *(const short8*)&wt[c * 128 + (k0 ^ ((c & 7) << 3))];
            acc[0][f] = __builtin_amdgcn_mfma_f32_16x16x32_bf16(a[0], b, acc[0][f], 0, 0, 0);
            acc[1][f] = __builtin_amdgcn_mfma_f32_16x16x32_bf16(a[1], b, acc[1][f], 0, 0, 0);
        }
    }

    // store D: row = row0 + mf*16 + (lane>>4)*4 + reg, col = f*16 + lm
    #pragma unroll
    for (int mf = 0; mf < 2; ++mf) {
        #pragma unroll
        for (int reg = 0; reg < 4; ++reg) {
            int r = row0 + mf * 16 + lg * 4 + reg;
            if (r >= nRows) continue;
            #pragma unroll
            for (int f = 0; f < 8; ++f)
                Y[(size_t)r * 128 + f * 16 + lm] = f2bf(acc[mf][f][reg]);
        }
    }
}

// O[d,:] = dinv[d]^2 * M[d,:] + sum_k coef_k * M[src_k,:]   (M bf16)
// one wave per dst row; lane owns channels {2l, 2l+1}; unroll x4.
// TO_OUT: write f32 split halves [z_mean | z_log]; else write bf16 Hb.
template<bool TO_OUT>
__global__ __launch_bounds__(256)
void gather_bf(const unsigned short* __restrict__ M,
               const int* __restrict__ rowptr,
               const unsigned int* __restrict__ csr,
               const float* __restrict__ dinv, void* __restrict__ O, int n) {
    int wid  = (blockIdx.x * 256 + threadIdx.x) >> 6;
    int lane = threadIdx.x & 63;
    if (wid >= n) return;
    const unsigned int* m2 = (const unsigned int*)M;   // 2 bf16 per uint

    float di = dinv[wid];
    unsigned int su = m2[(size_t)wid * 64 + lane];
    float c = di * di;
    float a0x = bf_lo(su) * c, a0y = bf_hi(su) * c;
    float a1x = 0.f, a1y = 0.f, a2x = 0.f, a2y = 0.f, a3x = 0.f, a3y = 0.f;

    int beg = __builtin_amdgcn_readfirstlane(rowptr[wid]);
    int end = __builtin_amdgcn_readfirstlane(rowptr[wid + 1]);

    int k = beg;
    for (; k + 3 < end; k += 4) {
        unsigned int e0 = csr[k],     e1 = csr[k + 1];
        unsigned int e2 = csr[k + 2], e3 = csr[k + 3];
        unsigned int u0 = m2[(size_t)(e0 >> 15) * 64 + lane];
        unsigned int u1 = m2[(size_t)(e1 >> 15) * 64 + lane];
        unsigned int u2 = m2[(size_t)(e2 >> 15) * 64 + lane];
        unsigned int u3 = m2[(size_t)(e3 >> 15) * 64 + lane];
        float w0 = __uint_as_float((e0 & 0x7fffu) << 16);
        float w1 = __uint_as_float((e1 & 0x7fffu) << 16);
        float w2 = __uint_as_float((e2 & 0x7fffu) << 16);
        float w3 = __uint_as_float((e3 & 0x7fffu) << 16);
        a0x += w0 * bf_lo(u0); a0y += w0 * bf_hi(u0);
        a1x += w1 * bf_lo(u1); a1y += w1 * bf_hi(u1);
        a2x += w2 * bf_lo(u2); a2y += w2 * bf_hi(u2);
        a3x += w3 * bf_lo(u3); a3y += w3 * bf_hi(u3);
    }
    for (; k < end; ++k) {
        unsigned int e0 = csr[k];
        unsigned int u0 = m2[(size_t)(e0 >> 15) * 64 + lane];
        float w0 = __uint_as_float((e0 & 0x7fffu) << 16);
        a0x += w0 * bf_lo(u0); a0y += w0 * bf_hi(u0);
    }
    float ax = (a0x + a1x) + (a2x + a3x);
    float ay = (a0y + a1y) + (a2y + a3y);

    if (!TO_OUT) {
        unsigned int o = (unsigned int)f2bf(ax) | ((unsigned int)f2bf(ay) << 16);
        ((unsigned int*)O)[(size_t)wid * 64 + lane] = o;
    } else {
        float* Of = (float*)O;
        float* dst = (lane < 32)
            ? Of + (size_t)wid * 64 + 2 * lane
            : Of + (size_t)n * 64 + (size_t)wid * 64 + 2 * (lane - 32);
        *(float2*)dst = make_float2(ax, ay);
    }
}

// column sums/sumsq over N rows of bf16 H (N x 128) -> stats[0:128]=sum,
// [128:256]=sumsq. Block reads contiguous 4KB per iteration (uint4/thread).
__global__ __launch_bounds__(256)
void bn_stats(const unsigned short* __restrict__ H, float* __restrict__ stats,
              int n) {
    const uint4* h4 = (const uint4*)H;            // 8 bf16 per uint4, 16/row
    const int tid = threadIdx.x;
    const int cg = tid & 15;                      // channel group (8 ch)
    const int rg = tid >> 4;                      // row-in-block 0..15
    float s[8] = {}, q[8] = {};
    for (int r = blockIdx.x * 16 + rg; r < n; r += gridDim.x * 16) {
        uint4 u = h4[(size_t)r * 16 + cg];        // flat = blk*256+tid: coalesced
        float v[8] = {bf_lo(u.x), bf_hi(u.x), bf_lo(u.y), bf_hi(u.y),
                      bf_lo(u.z), bf_hi(u.z), bf_lo(u.w), bf_hi(u.w)};
        #pragma unroll
        for (int j = 0; j < 8; ++j) { s[j] += v[j]; q[j] += v[j] * v[j]; }
    }
    __shared__ float ls[256][17];                 // pad to dodge bank aliasing
    #pragma unroll
    for (int j = 0; j < 8; ++j) { ls[tid][j] = s[j]; ls[tid][8 + j] = q[j]; }
    __syncthreads();
    if (tid < 128) {
        int c = tid, cgrp = c >> 3, j = c & 7;
        float S = 0.f, Q = 0.f;
        #pragma unroll
        for (int g = 0; g < 16; ++g) {
            S += ls[(g << 4) | cgrp][j];
            Q += ls[(g << 4) | cgrp][8 + j];
        }
        atomicAdd(&stats[c], S);
        atomicAdd(&stats[128 + c], Q);
    }
}

extern "C" void kernel_launch(void* const* d_in, const int* in_sizes, int n_in,
                              void* d_out, int out_size, void* d_ws, size_t ws_size,
                              hipStream_t stream) {
    const float* x    = (const float*)d_in[0];
    const int*   ei   = (const int*)d_in[1];
    const float* W0   = (const float*)d_in[2];
    const float* W1   = (const float*)d_in[3];
    const float* Wmu  = (const float*)d_in[4];
    const float* Wlog = (const float*)d_in[5];
    const float* g0   = (const float*)d_in[6];
    const float* b0   = (const float*)d_in[7];
    const float* g1   = (const float*)d_in[8];
    const float* b1   = (const float*)d_in[9];

    const int N_ = in_sizes[0] / 128;
    const int E_ = in_sizes[1] / 2;
    float* out = (float*)d_out;

    char* w = (char*)d_ws;
    auto carve = [&](size_t bytes) {
        char* p = w;
        w += (bytes + 255) & ~(size_t)255;
        return p;
    };
    // zeroed region first: cnt | stats0 | stats1 (single memset)
    int*   cnt    = (int*)  carve((size_t)N_ * 4);
    float* stats0 = (float*)carve(256 * 4);
    float* stats1 = (float*)carve(256 * 4);
    char*  zend   = w;
    float* dinv   = (float*)carve((size_t)N_ * 4);
    int*   rowptr = (int*)  carve((size_t)(N_ + 1) * 4);
    int*   cursor = (int*)  carve((size_t)(N_ + 1) * 4);
    int*   partials = (int*)carve(1024 * 4);
    unsigned int* csr = (unsigned int*)carve((size_t)E_ * 4);
    float* sc0    = (float*)carve(128 * 4);
    float* sh0    = (float*)carve(128 * 4);
    float* sc1    = (float*)carve(128 * 4);
    float* sh1    = (float*)carve(128 * 4);
    unsigned short* Mbf = (unsigned short*)carve((size_t)N_ * 128 * 2);
    unsigned short* Hb  = (unsigned short*)carve((size_t)N_ * 128 * 2);

    const int gGemm = (N_ + 127) / 128;
    const int gGath = (N_ * 64 + 255) / 256;       // one wave per node
    const int nb    = (N_ + 1023) / 1024;

    // ---- graph preprocessing: deg -> scan(+dinv) -> csr_fill ----
    hipMemsetAsync(cnt, 0, (size_t)(zend - (char*)cnt), stream);
    deg_count<<<(E_ + 255) / 256, 256, 0, stream>>>(ei, cnt, E_);
    scan_blocks<<<nb, 1024, 0, stream>>>(cnt, dinv, rowptr, partials, N_);
    scan_partials<<<1, 1024, 0, stream>>>(partials, rowptr + N_, nb);
    scan_add<<<(N_ + 255) / 256, 256, 0, stream>>>(rowptr, cursor, partials, N_);
    csr_fill<<<(E_ + 255) / 256, 256, 0, stream>>>(ei, dinv, cursor, csr, E_);

    // ---- layer 0 ----
    gemm_mfma<false, false, false><<<gGemm, 256, 0, stream>>>(
        x, W0, nullptr, nullptr, nullptr, Mbf, N_);
    gather_bf<false><<<gGath, 256, 0, stream>>>(Mbf, rowptr, csr, dinv, Hb, N_);
    bn_stats<<<512, 256, 0, stream>>>(Hb, stats0, N_);
    bn_coef<<<1, 128, 0, stream>>>(stats0, g0, b0, sc0, sh0, N_);

    // ---- layer 1 (BN0+ReLU fused into A-frag unpack) ----
    gemm_mfma<true, true, false><<<gGemm, 256, 0, stream>>>(
        Hb, W1, nullptr, sc0, sh0, Mbf, N_);
    gather_bf<false><<<gGath, 256, 0, stream>>>(Mbf, rowptr, csr, dinv, Hb, N_);
    bn_stats<<<512, 256, 0, stream>>>(Hb, stats1, N_);
    bn_coef<<<1, 128, 0, stream>>>(stats1, g1, b1, sc1, sh1, N_);

    // ---- heads (BN1+ReLU fused): Mh = relu(BN(Hb)) @ [Wmu|Wlog]; out = A^ Mh
    gemm_mfma<true, true, true><<<gGemm, 256, 0, stream>>>(
        Hb, Wmu, Wlog, sc1, sh1, Mbf, N_);
    gather_bf<true><<<gGath, 256, 0, stream>>>(Mbf, rowptr, csr, dinv, out, N_);
}

// Round 9
// 259.051 us; speedup vs baseline: 1.5335x; 1.0449x over previous
//
#include <hip/hip_runtime.h>
#include <hip/hip_bf16.h>

// ---------------------------------------------------------------------------
// GCN-VGAE encoder. Round 9 = Round 8 with two fixes:
//  - FIX: tickets+64 aliased dinv[0] (carve bug) -> sc1/sh1 never computed
//    (stayed 0xAA poison -> head output ~0). Each bn_stats now has its own
//    256B ticket slot inside the zeroed region.
//  - FIX: last-block ticket protocol: __syncthreads() BEFORE the ticket
//    increment (drains all waves' stats atomics), and the last block reads
//    stats with __hip_atomic_load(AGENT) (XCD-coherent), not volatile loads.
// Otherwise identical to R8: two-pass bucketed CSR sort, MFMA GEMMs,
// bf16 activations, packed 4B CSR, fused BN.
// ---------------------------------------------------------------------------

using short8 = __attribute__((ext_vector_type(8))) short;
using f32x4  = __attribute__((ext_vector_type(4))) float;

static __device__ __forceinline__ unsigned short f2bf(float f) {
    __hip_bfloat16 h = __float2bfloat16(f);
    return *reinterpret_cast<unsigned short*>(&h);
}
static __device__ __forceinline__ float bf_lo(unsigned int u) {
    return __uint_as_float(u << 16);
}
static __device__ __forceinline__ float bf_hi(unsigned int u) {
    return __uint_as_float(u & 0xffff0000u);
}
static __device__ __forceinline__ float bf2f(unsigned short u) {
    return __uint_as_float((unsigned int)u << 16);
}

__global__ __launch_bounds__(256)
void deg_count(const int* __restrict__ ei, int* __restrict__ cnt, int E_) {
    int e = blockIdx.x * 256 + threadIdx.x;
    if (e < E_) atomicAdd(&cnt[ei[E_ + e]], 1);   // row 1 = dst
}

// ---- hierarchical exclusive scan (dinv fused): cnt[0..n) -> rowptr[0..n] ----
__global__ __launch_bounds__(1024)
void scan_blocks(const int* __restrict__ cnt, float* __restrict__ dinv,
                 int* __restrict__ rowptr, int* __restrict__ partials, int n) {
    __shared__ int ls[1024];
    int tid = threadIdx.x;
    int i = blockIdx.x * 1024 + tid;
    int v = (i < n) ? cnt[i] : 0;
    if (i < n) dinv[i] = rsqrtf((float)v + 1.0f);
    ls[tid] = v;
    __syncthreads();
    #pragma unroll
    for (int off = 1; off < 1024; off <<= 1) {
        int t = (tid >= off) ? ls[tid - off] : 0;
        __syncthreads();
        ls[tid] += t;
        __syncthreads();
    }
    if (i < n) rowptr[i] = ls[tid] - v;           // local exclusive
    if (tid == 1023) partials[blockIdx.x] = ls[1023];
}

__global__ __launch_bounds__(1024)
void scan_partials(int* __restrict__ partials, int* __restrict__ rowptr_n,
                   int nb) {
    __shared__ int ls[1024];
    int tid = threadIdx.x;
    int v = (tid < nb) ? partials[tid] : 0;
    ls[tid] = v;
    __syncthreads();
    #pragma unroll
    for (int off = 1; off < 1024; off <<= 1) {
        int t = (tid >= off) ? ls[tid - off] : 0;
        __syncthreads();
        ls[tid] += t;
        __syncthreads();
    }
    if (tid < nb) partials[tid] = ls[tid] - v;    // exclusive block offsets
    if (tid == 1023) *rowptr_n = ls[1023];        // rowptr[n] = E
}

// add block offsets; also seed per-bucket claim cursors gcursor[b]=rowptr[b*128]
__global__ __launch_bounds__(256)
void scan_add(int* __restrict__ rowptr, int* __restrict__ gcursor,
              const int* __restrict__ partials, int n) {
    int i = blockIdx.x * 256 + threadIdx.x;
    if (i < n) {
        int v = rowptr[i] + partials[i >> 10];
        rowptr[i] = v;
        if ((i & 127) == 0) gcursor[i >> 7] = v;
    }
}

// ---- CSR build pass 1: bin edges into 128-node buckets ----
#define BCHUNK 4096
__global__ __launch_bounds__(256)
void bin_edges(const int* __restrict__ ei, const float* __restrict__ dinv,
               int* __restrict__ gcursor, uint2* __restrict__ binned, int E_) {
    __shared__ int hist[512];
    __shared__ int gbase[512];
    __shared__ int cur[512];
    const int tid = threadIdx.x;
    const int e0 = blockIdx.x * BCHUNK;

    #pragma unroll
    for (int q = 0; q < 2; ++q) hist[q * 256 + tid] = 0;
    __syncthreads();

    for (int i = tid; i < BCHUNK; i += 256) {
        int e = e0 + i;
        if (e < E_) atomicAdd(&hist[ei[E_ + e] >> 7], 1);
    }
    __syncthreads();

    #pragma unroll
    for (int q = 0; q < 2; ++q) {
        int b = q * 256 + tid;
        int c = hist[b];
        gbase[b] = c ? atomicAdd(&gcursor[b], c) : 0;
        cur[b] = 0;
    }
    __syncthreads();

    for (int i = tid; i < BCHUNK; i += 256) {
        int e = e0 + i;
        if (e >= E_) continue;
        int s = ei[e], d = ei[E_ + e];
        float coef = dinv[s] * dinv[d];
        unsigned int cb = (__float_as_uint(coef) + 0x8000u) >> 16;  // RN bf16
        unsigned int entry = ((unsigned int)s << 15) | (cb & 0x7fffu);
        int b = d >> 7;
        int p = gbase[b] + atomicAdd(&cur[b], 1);
        binned[p] = make_uint2(entry, (unsigned int)(d & 127));
    }
}

// ---- CSR build pass 2: exact placement within each bucket ----
__global__ __launch_bounds__(256)
void place_edges(const uint2* __restrict__ binned, const int* __restrict__ rowptr,
                 unsigned int* __restrict__ csr, int n) {
    __shared__ int cur[128];
    const int tid = threadIdx.x;
    const int n0 = blockIdx.x * 128;
    const int nn = min(128, n - n0);
    if (tid < nn) cur[tid] = rowptr[n0 + tid];
    __syncthreads();
    const int beg = rowptr[n0];
    const int end = rowptr[min(n0 + 128, n)];
    for (int i = beg + tid; i < end; i += 256) {
        uint2 v = binned[i];
        int p = atomicAdd(&cur[v.y], 1);
        csr[p] = v.x;
    }
}

// ---------------------------------------------------------------------------
// MFMA GEMM: Y(bf16 N x 128) = act(X) @ W, K=128. (unchanged from R7)
// ---------------------------------------------------------------------------
template<bool XBF, bool FUSE_BN, bool SPLIT_W>
__global__ __launch_bounds__(256)
void gemm_mfma(const void* __restrict__ Xv, const float* __restrict__ Wa,
               const float* __restrict__ Wb, const float* __restrict__ sc,
               const float* __restrict__ sh, unsigned short* __restrict__ Y,
               int nRows) {
    __shared__ unsigned short wt[128 * 128];  // [c][k] bf16, k XOR-swizzled

    const int tid = threadIdx.x;

    #pragma unroll
    for (int it = 0; it < 16; ++it) {
        int flat4 = it * 256 + tid;          // float4 index over 16384 floats
        int k  = flat4 >> 5;
        int c0 = (flat4 & 31) * 4;
        const float* srcp;
        if (!SPLIT_W) srcp = Wa + k * 128 + c0;
        else          srcp = (c0 < 64) ? (Wa + k * 64 + c0)
                                       : (Wb + k * 64 + (c0 - 64));
        float4 v = *(const float4*)srcp;
        float vv[4] = {v.x, v.y, v.z, v.w};
        #pragma unroll
        for (int j = 0; j < 4; ++j) {
            int c = c0 + j;
            wt[c * 128 + (k ^ ((c & 7) << 3))] = f2bf(vv[j]);
        }
    }
    __syncthreads();

    const int lane = tid & 63;
    const int wv   = tid >> 6;
    const int lm   = lane & 15;              // frag row (A) / col (B,D)
    const int lg   = lane >> 4;              // k-group
    const int row0 = blockIdx.x * 128 + wv * 32;

    f32x4 acc[2][8] = {};

    #pragma unroll
    for (int ks = 0; ks < 4; ++ks) {
        const int k0 = ks * 32 + lg * 8;

        short8 a[2];
        #pragma unroll
        for (int mf = 0; mf < 2; ++mf) {
            int r = row0 + mf * 16 + lm;
            if (r < nRows) {
                if (XBF) {
                    a[mf] = *(const short8*)((const unsigned short*)Xv +
                                             (size_t)r * 128 + k0);
                    if (FUSE_BN) {
                        float4 s0 = *(const float4*)(sc + k0);
                        float4 s1 = *(const float4*)(sc + k0 + 4);
                        float4 h0 = *(const float4*)(sh + k0);
                        float4 h1 = *(const float4*)(sh + k0 + 4);
                        float sv[8] = {s0.x, s0.y, s0.z, s0.w, s1.x, s1.y, s1.z, s1.w};
                        float hv[8] = {h0.x, h0.y, h0.z, h0.w, h1.x, h1.y, h1.z, h1.w};
                        #pragma unroll
                        for (int j = 0; j < 8; ++j) {
                            float v = bf2f((unsigned short)a[mf][j]);
                            v = fmaxf(v * sv[j] + hv[j], 0.f);
                            a[mf][j] = (short)f2bf(v);
                        }
                    }
                } else {
                    const float* xp = (const float*)Xv + (size_t)r * 128 + k0;
                    float4 p0 = *(const float4*)xp;
                    float4 p1 = *(const float4*)(xp + 4);
                    float pv[8] = {p0.x, p0.y, p0.z, p0.w, p1.x, p1.y, p1.z, p1.w};
                    #pragma unroll
                    for (int j = 0; j < 8; ++j) a[mf][j] = (short)f2bf(pv[j]);
                }
            } else {
                a[mf] = short8{};
            }
        }

        #pragma unroll
        for (int f = 0; f < 8; ++f) {
            int c = f * 16 + lm;
            short8 b = *(const short8*)&wt[c * 128 + (k0 ^ ((c & 7) << 3))];
            acc[0][f] = __builtin_amdgcn_mfma_f32_16x16x32_bf16(a[0], b, acc[0][f], 0, 0, 0);
            acc[1][f] = __builtin_amdgcn_mfma_f32_16x16x32_bf16(a[1], b, acc[1][f], 0, 0, 0);
        }
    }

    #pragma unroll
    for (int mf = 0; mf < 2; ++mf) {
        #pragma unroll
        for (int reg = 0; reg < 4; ++reg) {
            int r = row0 + mf * 16 + lg * 4 + reg;
            if (r >= nRows) continue;
            #pragma unroll
            for (int f = 0; f < 8; ++f)
                Y[(size_t)r * 128 + f * 16 + lm] = f2bf(acc[mf][f][reg]);
        }
    }
}

// O[d,:] = dinv[d]^2 * M[d,:] + sum_k coef_k * M[src_k,:]   (M bf16)
template<bool TO_OUT>
__global__ __launch_bounds__(256)
void gather_bf(const unsigned short* __restrict__ M,
               const int* __restrict__ rowptr,
               const unsigned int* __restrict__ csr,
               const float* __restrict__ dinv, void* __restrict__ O, int n) {
    int wid  = (blockIdx.x * 256 + threadIdx.x) >> 6;
    int lane = threadIdx.x & 63;
    if (wid >= n) return;
    const unsigned int* m2 = (const unsigned int*)M;   // 2 bf16 per uint

    float di = dinv[wid];
    unsigned int su = m2[(size_t)wid * 64 + lane];
    float c = di * di;
    float a0x = bf_lo(su) * c, a0y = bf_hi(su) * c;
    float a1x = 0.f, a1y = 0.f, a2x = 0.f, a2y = 0.f, a3x = 0.f, a3y = 0.f;

    int beg = __builtin_amdgcn_readfirstlane(rowptr[wid]);
    int end = __builtin_amdgcn_readfirstlane(rowptr[wid + 1]);

    int k = beg;
    for (; k + 3 < end; k += 4) {
        unsigned int e0 = csr[k],     e1 = csr[k + 1];
        unsigned int e2 = csr[k + 2], e3 = csr[k + 3];
        unsigned int u0 = m2[(size_t)(e0 >> 15) * 64 + lane];
        unsigned int u1 = m2[(size_t)(e1 >> 15) * 64 + lane];
        unsigned int u2 = m2[(size_t)(e2 >> 15) * 64 + lane];
        unsigned int u3 = m2[(size_t)(e3 >> 15) * 64 + lane];
        float w0 = __uint_as_float((e0 & 0x7fffu) << 16);
        float w1 = __uint_as_float((e1 & 0x7fffu) << 16);
        float w2 = __uint_as_float((e2 & 0x7fffu) << 16);
        float w3 = __uint_as_float((e3 & 0x7fffu) << 16);
        a0x += w0 * bf_lo(u0); a0y += w0 * bf_hi(u0);
        a1x += w1 * bf_lo(u1); a1y += w1 * bf_hi(u1);
        a2x += w2 * bf_lo(u2); a2y += w2 * bf_hi(u2);
        a3x += w3 * bf_lo(u3); a3y += w3 * bf_hi(u3);
    }
    for (; k < end; ++k) {
        unsigned int e0 = csr[k];
        unsigned int u0 = m2[(size_t)(e0 >> 15) * 64 + lane];
        float w0 = __uint_as_float((e0 & 0x7fffu) << 16);
        a0x += w0 * bf_lo(u0); a0y += w0 * bf_hi(u0);
    }
    float ax = (a0x + a1x) + (a2x + a3x);
    float ay = (a0y + a1y) + (a2y + a3y);

    if (!TO_OUT) {
        unsigned int o = (unsigned int)f2bf(ax) | ((unsigned int)f2bf(ay) << 16);
        ((unsigned int*)O)[(size_t)wid * 64 + lane] = o;
    } else {
        float* Of = (float*)O;
        float* dst = (lane < 32)
            ? Of + (size_t)wid * 64 + 2 * lane
            : Of + (size_t)n * 64 + (size_t)wid * 64 + 2 * (lane - 32);
        *(float2*)dst = make_float2(ax, ay);
    }
}

// column sums/sumsq over N rows of bf16 H + FUSED bn_coef via last-block
// ticket. Protocol: all stats atomics -> __syncthreads (drains every wave's
// outstanding atomics) -> tid0 ticket atomicAdd -> last block reads stats
// with AGENT-scope atomic loads (coherent across XCDs) and writes sc/sh.
__global__ __launch_bounds__(256)
void bn_stats(const unsigned short* __restrict__ H, float* __restrict__ stats,
              const float* __restrict__ gamma, const float* __restrict__ beta,
              float* __restrict__ sc, float* __restrict__ sh,
              unsigned int* __restrict__ ticket, int n) {
    const uint4* h4 = (const uint4*)H;            // 8 bf16 per uint4, 16/row
    const int tid = threadIdx.x;
    const int cg = tid & 15;                      // channel group (8 ch)
    const int rg = tid >> 4;                      // row-in-block 0..15
    float s[8] = {}, q[8] = {};
    for (int r = blockIdx.x * 16 + rg; r < n; r += gridDim.x * 16) {
        uint4 u = h4[(size_t)r * 16 + cg];        // coalesced 4KB/block/iter
        float v[8] = {bf_lo(u.x), bf_hi(u.x), bf_lo(u.y), bf_hi(u.y),
                      bf_lo(u.z), bf_hi(u.z), bf_lo(u.w), bf_hi(u.w)};
        #pragma unroll
        for (int j = 0; j < 8; ++j) { s[j] += v[j]; q[j] += v[j] * v[j]; }
    }
    __shared__ float ls[256][17];                 // pad to dodge bank aliasing
    #pragma unroll
    for (int j = 0; j < 8; ++j) { ls[tid][j] = s[j]; ls[tid][8 + j] = q[j]; }
    __syncthreads();
    if (tid < 128) {
        int cgrp = tid >> 3, j = tid & 7;
        float S = 0.f, Q = 0.f;
        #pragma unroll
        for (int g = 0; g < 16; ++g) {
            S += ls[(g << 4) | cgrp][j];
            Q += ls[(g << 4) | cgrp][8 + j];
        }
        atomicAdd(&stats[tid], S);
        atomicAdd(&stats[128 + tid], Q);
    }
    // drain ALL waves' stats atomics before publishing this block's ticket
    __syncthreads();
    __shared__ int lastFlag;
    if (tid == 0) {
        __threadfence();
        unsigned int t = atomicAdd(ticket, 1u);
        lastFlag = (t == gridDim.x - 1);
    }
    __syncthreads();
    if (lastFlag && tid < 128) {
        float Ssum = __hip_atomic_load(&stats[tid], __ATOMIC_RELAXED,
                                       __HIP_MEMORY_SCOPE_AGENT);
        float Qsum = __hip_atomic_load(&stats[128 + tid], __ATOMIC_RELAXED,
                                       __HIP_MEMORY_SCOPE_AGENT);
        float inv_n = 1.0f / (float)n;
        float mean = Ssum * inv_n;
        float var  = Qsum * inv_n - mean * mean;
        float sv = rsqrtf(var + 1e-5f) * gamma[tid];
        sc[tid] = sv;
        sh[tid] = beta[tid] - mean * sv;
    }
}

extern "C" void kernel_launch(void* const* d_in, const int* in_sizes, int n_in,
                              void* d_out, int out_size, void* d_ws, size_t ws_size,
                              hipStream_t stream) {
    const float* x    = (const float*)d_in[0];
    const int*   ei   = (const int*)d_in[1];
    const float* W0   = (const float*)d_in[2];
    const float* W1   = (const float*)d_in[3];
    const float* Wmu  = (const float*)d_in[4];
    const float* Wlog = (const float*)d_in[5];
    const float* g0   = (const float*)d_in[6];
    const float* b0   = (const float*)d_in[7];
    const float* g1   = (const float*)d_in[8];
    const float* b1   = (const float*)d_in[9];

    const int N_ = in_sizes[0] / 128;
    const int E_ = in_sizes[1] / 2;
    float* out = (float*)d_out;

    char* w = (char*)d_ws;
    auto carve = [&](size_t bytes) {
        char* p = w;
        w += (bytes + 255) & ~(size_t)255;
        return p;
    };
    // zeroed region first: cnt | stats0 | stats1 | ticket0 | ticket1
    int*   cnt     = (int*)  carve((size_t)N_ * 4);
    float* stats0  = (float*)carve(256 * 4);
    float* stats1  = (float*)carve(256 * 4);
    unsigned int* ticket0 = (unsigned int*)carve(256);
    unsigned int* ticket1 = (unsigned int*)carve(256);
    char*  zend    = w;
    float* dinv    = (float*)carve((size_t)N_ * 4);
    int*   rowptr  = (int*)  carve((size_t)(N_ + 1) * 4);
    int*   gcursor = (int*)  carve(512 * 4);
    int*   partials= (int*)  carve(1024 * 4);
    unsigned int* csr = (unsigned int*)carve((size_t)E_ * 4);
    uint2* binned  = (uint2*)carve((size_t)E_ * 8);
    float* sc0     = (float*)carve(128 * 4);
    float* sh0     = (float*)carve(128 * 4);
    float* sc1     = (float*)carve(128 * 4);
    float* sh1     = (float*)carve(128 * 4);
    unsigned short* Mbf = (unsigned short*)carve((size_t)N_ * 128 * 2);
    unsigned short* Hb  = (unsigned short*)carve((size_t)N_ * 128 * 2);

    const int gGemm = (N_ + 127) / 128;
    const int gGath = (N_ * 64 + 255) / 256;       // one wave per node
    const int nb    = (N_ + 1023) / 1024;
    const int nbk   = (N_ + 127) / 128;            // buckets (<=512)
    const int gBin  = (E_ + BCHUNK - 1) / BCHUNK;

    // ---- graph preprocessing ----
    hipMemsetAsync(cnt, 0, (size_t)(zend - (char*)cnt), stream);
    deg_count<<<(E_ + 255) / 256, 256, 0, stream>>>(ei, cnt, E_);
    scan_blocks<<<nb, 1024, 0, stream>>>(cnt, dinv, rowptr, partials, N_);
    scan_partials<<<1, 1024, 0, stream>>>(partials, rowptr + N_, nb);
    scan_add<<<(N_ + 255) / 256, 256, 0, stream>>>(rowptr, gcursor, partials, N_);
    bin_edges<<<gBin, 256, 0, stream>>>(ei, dinv, gcursor, binned, E_);
    place_edges<<<nbk, 256, 0, stream>>>(binned, rowptr, csr, N_);

    // ---- layer 0 ----
    gemm_mfma<false, false, false><<<gGemm, 256, 0, stream>>>(
        x, W0, nullptr, nullptr, nullptr, Mbf, N_);
    gather_bf<false><<<gGath, 256, 0, stream>>>(Mbf, rowptr, csr, dinv, Hb, N_);
    bn_stats<<<512, 256, 0, stream>>>(Hb, stats0, g0, b0, sc0, sh0, ticket0, N_);

    // ---- layer 1 (BN0+ReLU fused into A-frag unpack) ----
    gemm_mfma<true, true, false><<<gGemm, 256, 0, stream>>>(
        Hb, W1, nullptr, sc0, sh0, Mbf, N_);
    gather_bf<false><<<gGath, 256, 0, stream>>>(Mbf, rowptr, csr, dinv, Hb, N_);
    bn_stats<<<512, 256, 0, stream>>>(Hb, stats1, g1, b1, sc1, sh1, ticket1, N_);

    // ---- heads (BN1+ReLU fused): Mh = relu(BN(Hb)) @ [Wmu|Wlog]; out = A^ Mh
    gemm_mfma<true, true, true><<<gGemm, 256, 0, stream>>>(
        Hb, Wmu, Wlog, sc1, sh1, Mbf, N_);
    gather_bf<true><<<gGath, 256, 0, stream>>>(Mbf, rowptr, csr, dinv, out, N_);
}